// Round 11
// baseline (165.821 us; speedup 1.0000x reference)
//
#include <hip/hip_runtime.h>
#include <hip/hip_bf16.h>

#define B_ROWS 16384
#define D_DIM  1024
#define F_DIM  1031
#define KP     1088   // padded K (17 * 64)
#define NP     1152   // padded N / hidden stride (9 * 128)
#define NT_N   9
#define NT_M   128
#define TBUF   (128 * 64)   // one LDS tile (elements)

typedef __attribute__((ext_vector_type(4))) float  f32x4;
typedef __attribute__((ext_vector_type(8))) short  bf16x8;

__device__ __forceinline__ unsigned short f2bf(float f) {
    unsigned int x = __float_as_uint(f);
    unsigned int r = (x + 0x7fffu + ((x >> 16) & 1u)) >> 16;
    return (unsigned short)r;
}
__device__ __forceinline__ float bf2f(unsigned short u) {
    return __uint_as_float((unsigned int)u << 16);
}
__device__ __forceinline__ void gload16(const void* g, void* l) {
    __builtin_amdgcn_global_load_lds(
        (const __attribute__((address_space(1))) void*)g,
        (__attribute__((address_space(3))) void*)l, 16, 0, 0);
}

// ---------------- Kernel 1a: vc/vb stats (wave = 1 row; 2 streams only) ---------------
__global__ __launch_bounds__(256) void k_vstats(
        const float* __restrict__ vc, const float* __restrict__ vb,
        unsigned short* __restrict__ featpad) {
    int tid  = threadIdx.x;
    int lane = tid & 63;
    int row  = blockIdx.x * 4 + (tid >> 6);

    const float4* c4 = (const float4*)(vc + (size_t)row * D_DIM);
    const float4* b4 = (const float4*)(vb + (size_t)row * D_DIM);

    float4 cv[4], bv[4];
    #pragma unroll
    for (int b = 0; b < 4; ++b) { cv[b] = c4[lane + 64 * b]; bv[b] = b4[lane + 64 * b]; }

    float nc = 0.f, nb = 0.f, dcb = 0.f;
    #pragma unroll
    for (int b = 0; b < 4; ++b) {
        nc  += cv[b].x*cv[b].x + cv[b].y*cv[b].y + cv[b].z*cv[b].z + cv[b].w*cv[b].w;
        nb  += bv[b].x*bv[b].x + bv[b].y*bv[b].y + bv[b].z*bv[b].z + bv[b].w*bv[b].w;
        dcb += cv[b].x*bv[b].x + cv[b].y*bv[b].y + cv[b].z*bv[b].z + cv[b].w*bv[b].w;
    }
    #pragma unroll
    for (int o = 1; o < 64; o <<= 1) {
        nc  += __shfl_xor(nc,  o);
        nb  += __shfl_xor(nb,  o);
        dcb += __shfl_xor(dcb, o);
    }

    float rc = sqrtf(nc), rb = sqrtf(nb);
    float mc = fmaxf(rc, 1e-12f), mb = fmaxf(rb, 1e-12f);
    float align = dcb / (mc * mb);
    float t2 = nc/(mc*mc) - 2.f*dcb/(mc*mb) + nb/(mb*mb);
    t2 = fmaxf(t2, 0.f);
    float scal[6];
    scal[0] = align;
    scal[1] = sqrtf(t2);
    scal[2] = t2;
    scal[3] = sqrtf(fmaxf(nc - 2.f*dcb + nb, 0.f));
    scal[4] = rc; scal[5] = rb;

    // tail cols 1024..1087, skipping 1030 (r_final, written by k_hconv)
    unsigned short* orow = featpad + (size_t)row * KP;
    if (lane != 6) {
        float v = (lane < 6) ? scal[lane] : 0.f;
        orow[1024 + lane] = f2bf(v);
    }
}

// ---------------- Kernel 1b: h -> bf16 + r_final (wave = 2 rows; 1 stream) ------------
__global__ __launch_bounds__(256) void k_hconv(
        const float* __restrict__ h, unsigned short* __restrict__ featpad) {
    int tid  = threadIdx.x;
    int lane = tid & 63;
    int row0 = blockIdx.x * 8 + (tid >> 6) * 2;   // this wave: rows row0, row0+1

    const float4* h40 = (const float4*)(h + (size_t)row0 * D_DIM);
    const float4* h41 = (const float4*)(h + (size_t)(row0 + 1) * D_DIM);

    float4 hv0[4], hv1[4];
    #pragma unroll
    for (int b = 0; b < 4; ++b) { hv0[b] = h40[lane + 64 * b]; hv1[b] = h41[lane + 64 * b]; }

    float nh0 = 0.f, nh1 = 0.f;
    #pragma unroll
    for (int b = 0; b < 4; ++b) {
        nh0 += hv0[b].x*hv0[b].x + hv0[b].y*hv0[b].y + hv0[b].z*hv0[b].z + hv0[b].w*hv0[b].w;
        nh1 += hv1[b].x*hv1[b].x + hv1[b].y*hv1[b].y + hv1[b].z*hv1[b].z + hv1[b].w*hv1[b].w;
    }
    #pragma unroll
    for (int o = 1; o < 64; o <<= 1) {
        nh0 += __shfl_xor(nh0, o);
        nh1 += __shfl_xor(nh1, o);
    }

    unsigned short* orow0 = featpad + (size_t)row0 * KP;
    unsigned short* orow1 = orow0 + KP;
    #pragma unroll
    for (int b = 0; b < 4; ++b) {
        union { unsigned int u[2]; unsigned short us[4]; } w0, w1;
        w0.us[0] = f2bf(hv0[b].x); w0.us[1] = f2bf(hv0[b].y);
        w0.us[2] = f2bf(hv0[b].z); w0.us[3] = f2bf(hv0[b].w);
        w1.us[0] = f2bf(hv1[b].x); w1.us[1] = f2bf(hv1[b].y);
        w1.us[2] = f2bf(hv1[b].z); w1.us[3] = f2bf(hv1[b].w);
        *(uint2*)(orow0 + 4 * (lane + 64 * b)) = *(uint2*)w0.u;
        *(uint2*)(orow1 + 4 * (lane + 64 * b)) = *(uint2*)w1.u;
    }
    if (lane == 0) orow0[1030] = f2bf(sqrtf(nh0));
    if (lane == 1) orow1[1030] = f2bf(sqrtf(nh1));
}

// ---------------- Kernel 2: W1 -> W1^T bf16, padded, linear ----------------
__global__ __launch_bounds__(256) void k_w1t(const float* __restrict__ W1,
                                             unsigned short* __restrict__ w1t) {
    int idx = blockIdx.x * 256 + threadIdx.x;
    if (idx >= NP * KP) return;
    int n = idx / KP, c = idx % KP;
    float v = 0.f;
    if (n < F_DIM && c < F_DIM) v = W1[(size_t)c * F_DIM + n];
    w1t[idx] = f2bf(v);
}

// ---------------- Kernel 3: GEMM1 (+b1, ReLU) -> bf16 hidden --------------------------
// m97 structure + T3 minimum-2-phase double-buffer: issue next tile's global_load_lds
// into buf^1 BEFORE computing buf; single __syncthreads per K-step (its implicit
// vmcnt(0) drain lands after compute has hidden the load latency).
__global__ __launch_bounds__(256, 1) void k_gemm(
        const unsigned short* __restrict__ A,   // featpad [16384][1088]
        const unsigned short* __restrict__ Bt,  // w1t [1152][1088]
        const float* __restrict__ b1,
        unsigned short* __restrict__ hidden) {  // [16384][1152]
    __shared__ unsigned short As[2 * TBUF];   // 32 KB, linear, double-buffered
    __shared__ unsigned short Bs[2 * TBUF];   // 32 KB
    __shared__ float b1s[128];

    int tid = threadIdx.x;
    int lane = tid & 63;
    int wid = tid >> 6;

    // XCD-aware mapping (bijective): 9 nt-blocks per A panel on one XCD.
    int id = blockIdx.x;            // 0..1151
    int xcd = id & 7;
    int slot = id >> 3;             // 0..143
    int mt = xcd * 16 + slot / NT_N;
    int nt = slot % NT_N;

    if (tid < 128) {
        int ncol = nt * 128 + tid;
        b1s[tid] = (ncol < F_DIM) ? b1[ncol] : 0.f;
    }

    f32x4 acc[4][4] = {};
    int wm = wid >> 1, wn = wid & 1;

    const unsigned short* aSrc = A  + ((size_t)(mt * 128 + wid * 32 + (lane >> 3))) * KP + (lane & 7) * 8;
    const unsigned short* bSrc = Bt + ((size_t)(nt * 128 + wid * 32 + (lane >> 3))) * KP + (lane & 7) * 8;
    int dstOff = wid * 32 * 64;   // wave-uniform LDS offset within a tile buffer

    // prologue: stage tile 0 into buf 0
    #pragma unroll
    for (int i = 0; i < 4; ++i) {
        gload16(aSrc + (size_t)i * 8 * KP, As + dstOff + i * 8 * 64);
        gload16(bSrc + (size_t)i * 8 * KP, Bs + dstOff + i * 8 * 64);
    }
    __syncthreads();   // drains vmcnt(0): tile 0 resident

    int cur = 0;
    for (int kt = 0; kt < KP / 64; ++kt) {
        // issue next tile's loads into the other buffer (overlaps with compute below)
        if (kt + 1 < KP / 64) {
            int nxt = (cur ^ 1) * TBUF;
            #pragma unroll
            for (int i = 0; i < 4; ++i) {
                gload16(aSrc + (kt + 1) * 64 + (size_t)i * 8 * KP, As + nxt + dstOff + i * 8 * 64);
                gload16(bSrc + (kt + 1) * 64 + (size_t)i * 8 * KP, Bs + nxt + dstOff + i * 8 * 64);
            }
        }
        const unsigned short* asb = As + cur * TBUF;
        const unsigned short* bsb = Bs + cur * TBUF;
        #pragma unroll
        for (int kk = 0; kk < 2; ++kk) {
            bf16x8 af[4], bfr[4];
            int klane = kk * 32 + ((lane >> 4) << 3);
            #pragma unroll
            for (int m = 0; m < 4; ++m) {
                int arow = wm * 64 + m * 16 + (lane & 15);
                af[m] = *(const bf16x8*)&asb[arow * 64 + klane];
            }
            #pragma unroll
            for (int n = 0; n < 4; ++n) {
                int brow = wn * 64 + n * 16 + (lane & 15);
                bfr[n] = *(const bf16x8*)&bsb[brow * 64 + klane];
            }
            #pragma unroll
            for (int m = 0; m < 4; ++m)
                #pragma unroll
                for (int n = 0; n < 4; ++n)
                    acc[m][n] = __builtin_amdgcn_mfma_f32_16x16x32_bf16(af[m], bfr[n], acc[m][n], 0, 0, 0);
        }
        __syncthreads();   // next tile landed (vmcnt0) + all reads of cur done
        cur ^= 1;
    }

    #pragma unroll
    for (int m = 0; m < 4; ++m) {
        #pragma unroll
        for (int n = 0; n < 4; ++n) {
            int coll = wn * 64 + n * 16 + (lane & 15);
            int col = nt * 128 + coll;
            #pragma unroll
            for (int r = 0; r < 4; ++r) {
                int row = mt * 128 + wm * 64 + m * 16 + ((lane >> 4) << 2) + r;
                float v = acc[m][n][r] + b1s[coll];
                hidden[(size_t)row * NP + col] = f2bf(fmaxf(v, 0.f));
            }
        }
    }
}

// ---------------- Kernel 4: out = hidden @ W2 + b2 (memory-bound stream) -------------
__global__ __launch_bounds__(256) void k_head(const unsigned short* __restrict__ hidden,
                                              const float* __restrict__ W2,
                                              const float* __restrict__ b2,
                                              float* __restrict__ out) {
    __shared__ float W2s[NP * 5];   // 23,040 B
    int tid = threadIdx.x;
    for (int idx = tid; idx < NP * 5; idx += 256) {
        int n = idx / 5, j = idx % 5;
        W2s[idx] = (n < F_DIM) ? W2[n * 5 + j] : 0.f;
    }
    __syncthreads();

    int wid = tid >> 6, lane = tid & 63;
    int row = blockIdx.x * 16 + wid * 4 + (lane >> 4);   // 16 rows/block
    int seg = lane & 15;                                  // 16 lanes per row, 72 cols each
    const unsigned short* hr = hidden + (size_t)row * NP + seg * 72;

    float s[5] = {0.f, 0.f, 0.f, 0.f, 0.f};
    #pragma unroll
    for (int c = 0; c < 9; ++c) {
        union { uint4 v; unsigned short us[8]; } pk;
        pk.v = *(const uint4*)(hr + c * 8);
        #pragma unroll
        for (int e = 0; e < 8; ++e) {
            float hv = bf2f(pk.us[e]);
            int col = seg * 72 + c * 8 + e;
            #pragma unroll
            for (int j = 0; j < 5; ++j) s[j] += hv * W2s[col * 5 + j];
        }
    }
    #pragma unroll
    for (int o = 1; o < 16; o <<= 1) {
        #pragma unroll
        for (int j = 0; j < 5; ++j) s[j] += __shfl_xor(s[j], o);
    }
    if (seg == 0) {
        #pragma unroll
        for (int j = 0; j < 5; ++j) out[(size_t)row * 5 + j] = s[j] + b2[j];
    }
}

extern "C" void kernel_launch(void* const* d_in, const int* in_sizes, int n_in,
                              void* d_out, int out_size, void* d_ws, size_t ws_size,
                              hipStream_t stream) {
    const float* h_final   = (const float*)d_in[0];
    const float* v_current = (const float*)d_in[1];
    const float* v_basin   = (const float*)d_in[2];
    const float* W1        = (const float*)d_in[3];
    const float* b1        = (const float*)d_in[4];
    const float* W2        = (const float*)d_in[5];
    const float* b2        = (const float*)d_in[6];
    float* out = (float*)d_out;

    char* ws = (char*)d_ws;
    unsigned short* featpad = (unsigned short*)ws;                       // 16384*1088*2 = 35,651,584 B
    unsigned short* w1t     = (unsigned short*)(ws + 35651584);          // 1152*1088*2  =  2,506,752 B
    unsigned short* hidden  = (unsigned short*)(ws + 35651584 + 2506752);// 16384*1152*2 = 37,748,736 B

    k_vstats<<<dim3(B_ROWS / 4), dim3(256), 0, stream>>>(v_current, v_basin, featpad);
    k_hconv<<<dim3(B_ROWS / 8), dim3(256), 0, stream>>>(h_final, featpad);
    k_w1t<<<dim3((NP * KP + 255) / 256), dim3(256), 0, stream>>>(W1, w1t);
    k_gemm<<<dim3(NT_N * NT_M), dim3(256), 0, stream>>>(featpad, w1t, b1, hidden);
    k_head<<<dim3(B_ROWS / 16), dim3(256), 0, stream>>>(hidden, W2, b2, out);
}

// Round 12
// 143.268 us; speedup vs baseline: 1.1574x; 1.1574x over previous
//
#include <hip/hip_runtime.h>
#include <hip/hip_bf16.h>

#define B_ROWS 16384
#define D_DIM  1024
#define F_DIM  1031
#define KP     1088   // padded K (17 * 64)
#define NP     1152   // padded N (9 * 128)
#define NT_N   9
#define NT_M   128

typedef __attribute__((ext_vector_type(4))) float  f32x4;
typedef __attribute__((ext_vector_type(8))) short  bf16x8;

__device__ __forceinline__ unsigned short f2bf(float f) {
    unsigned int x = __float_as_uint(f);
    unsigned int r = (x + 0x7fffu + ((x >> 16) & 1u)) >> 16;
    return (unsigned short)r;
}
__device__ __forceinline__ void gload16(const void* g, void* l) {
    __builtin_amdgcn_global_load_lds(
        (const __attribute__((address_space(1))) void*)g,
        (__attribute__((address_space(3))) void*)l, 16, 0, 0);
}

// ---------------- Kernel 1a: vc/vb stats (wave = 1 row) ---------------
__global__ __launch_bounds__(256) void k_vstats(
        const float* __restrict__ vc, const float* __restrict__ vb,
        unsigned short* __restrict__ featpad) {
    int tid  = threadIdx.x;
    int lane = tid & 63;
    int row  = blockIdx.x * 4 + (tid >> 6);

    const float4* c4 = (const float4*)(vc + (size_t)row * D_DIM);
    const float4* b4 = (const float4*)(vb + (size_t)row * D_DIM);

    float4 cv[4], bv[4];
    #pragma unroll
    for (int b = 0; b < 4; ++b) { cv[b] = c4[lane + 64 * b]; bv[b] = b4[lane + 64 * b]; }

    float nc = 0.f, nb = 0.f, dcb = 0.f;
    #pragma unroll
    for (int b = 0; b < 4; ++b) {
        nc  += cv[b].x*cv[b].x + cv[b].y*cv[b].y + cv[b].z*cv[b].z + cv[b].w*cv[b].w;
        nb  += bv[b].x*bv[b].x + bv[b].y*bv[b].y + bv[b].z*bv[b].z + bv[b].w*bv[b].w;
        dcb += cv[b].x*bv[b].x + cv[b].y*bv[b].y + cv[b].z*bv[b].z + cv[b].w*bv[b].w;
    }
    #pragma unroll
    for (int o = 1; o < 64; o <<= 1) {
        nc  += __shfl_xor(nc,  o);
        nb  += __shfl_xor(nb,  o);
        dcb += __shfl_xor(dcb, o);
    }

    float rc = sqrtf(nc), rb = sqrtf(nb);
    float mc = fmaxf(rc, 1e-12f), mb = fmaxf(rb, 1e-12f);
    float align = dcb / (mc * mb);
    float t2 = nc/(mc*mc) - 2.f*dcb/(mc*mb) + nb/(mb*mb);
    t2 = fmaxf(t2, 0.f);
    float scal[6];
    scal[0] = align;
    scal[1] = sqrtf(t2);
    scal[2] = t2;
    scal[3] = sqrtf(fmaxf(nc - 2.f*dcb + nb, 0.f));
    scal[4] = rc; scal[5] = rb;

    unsigned short* orow = featpad + (size_t)row * KP;
    if (lane != 6) {
        float v = (lane < 6) ? scal[lane] : 0.f;
        orow[1024 + lane] = f2bf(v);
    }
}

// ---------------- Kernel 1b: h -> bf16 + r_final (wave = 2 rows) ------------
__global__ __launch_bounds__(256) void k_hconv(
        const float* __restrict__ h, unsigned short* __restrict__ featpad) {
    int tid  = threadIdx.x;
    int lane = tid & 63;
    int row0 = blockIdx.x * 8 + (tid >> 6) * 2;

    const float4* h40 = (const float4*)(h + (size_t)row0 * D_DIM);
    const float4* h41 = (const float4*)(h + (size_t)(row0 + 1) * D_DIM);

    float4 hv0[4], hv1[4];
    #pragma unroll
    for (int b = 0; b < 4; ++b) { hv0[b] = h40[lane + 64 * b]; hv1[b] = h41[lane + 64 * b]; }

    float nh0 = 0.f, nh1 = 0.f;
    #pragma unroll
    for (int b = 0; b < 4; ++b) {
        nh0 += hv0[b].x*hv0[b].x + hv0[b].y*hv0[b].y + hv0[b].z*hv0[b].z + hv0[b].w*hv0[b].w;
        nh1 += hv1[b].x*hv1[b].x + hv1[b].y*hv1[b].y + hv1[b].z*hv1[b].z + hv1[b].w*hv1[b].w;
    }
    #pragma unroll
    for (int o = 1; o < 64; o <<= 1) {
        nh0 += __shfl_xor(nh0, o);
        nh1 += __shfl_xor(nh1, o);
    }

    unsigned short* orow0 = featpad + (size_t)row0 * KP;
    unsigned short* orow1 = orow0 + KP;
    #pragma unroll
    for (int b = 0; b < 4; ++b) {
        union { unsigned int u[2]; unsigned short us[4]; } w0, w1;
        w0.us[0] = f2bf(hv0[b].x); w0.us[1] = f2bf(hv0[b].y);
        w0.us[2] = f2bf(hv0[b].z); w0.us[3] = f2bf(hv0[b].w);
        w1.us[0] = f2bf(hv1[b].x); w1.us[1] = f2bf(hv1[b].y);
        w1.us[2] = f2bf(hv1[b].z); w1.us[3] = f2bf(hv1[b].w);
        *(uint2*)(orow0 + 4 * (lane + 64 * b)) = *(uint2*)w0.u;
        *(uint2*)(orow1 + 4 * (lane + 64 * b)) = *(uint2*)w1.u;
    }
    if (lane == 0) orow0[1030] = f2bf(sqrtf(nh0));
    if (lane == 1) orow1[1030] = f2bf(sqrtf(nh1));
}

// ---------------- Kernel 2: W1 -> W1^T bf16, padded, linear ----------------
__global__ __launch_bounds__(256) void k_w1t(const float* __restrict__ W1,
                                             unsigned short* __restrict__ w1t) {
    int idx = blockIdx.x * 256 + threadIdx.x;
    if (idx >= NP * KP) return;
    int n = idx / KP, c = idx % KP;
    float v = 0.f;
    if (n < F_DIM && c < F_DIM) v = W1[(size_t)c * F_DIM + n];
    w1t[idx] = f2bf(v);
}

// ---------------- Kernel 3: GEMM1 + fused b1/ReLU/W2 epilogue -> partials -------------
// k-loop: r10-exact (single-buffer 2-barrier m97 structure, proven 65 us).
// Epilogue: in-register W2 reduction (no Hs tile, no hidden buffer).
__global__ __launch_bounds__(256, 1) void k_gemm(
        const unsigned short* __restrict__ A,   // featpad [16384][1088]
        const unsigned short* __restrict__ Bt,  // w1t [1152][1088]
        const float* __restrict__ b1, const float* __restrict__ W2,
        float* __restrict__ partials) {         // [NT_N][B_ROWS][5]
    __shared__ unsigned short As[128 * 64];   // 16 KB, linear
    __shared__ unsigned short Bs[128 * 64];   // 16 KB, linear
    __shared__ float b1s[128];
    __shared__ float W2s[128 * 5];
    __shared__ float ps[128][5];

    int tid = threadIdx.x;
    int lane = tid & 63;
    int wid = tid >> 6;

    // XCD-aware mapping (bijective): 9 nt-blocks per A panel on one XCD.
    int id = blockIdx.x;            // 0..1151
    int xcd = id & 7;
    int slot = id >> 3;             // 0..143
    int mt = xcd * 16 + slot / NT_N;
    int nt = slot % NT_N;

    if (tid < 128) {
        int ncol = nt * 128 + tid;
        bool valid = ncol < F_DIM;
        b1s[tid] = valid ? b1[ncol] : 0.f;
        #pragma unroll
        for (int j = 0; j < 5; ++j) W2s[tid * 5 + j] = valid ? W2[ncol * 5 + j] : 0.f;
    }

    f32x4 acc[4][4] = {};
    int wm = wid >> 1, wn = wid & 1;

    const unsigned short* aSrc = A  + ((size_t)(mt * 128 + wid * 32 + (lane >> 3))) * KP + (lane & 7) * 8;
    const unsigned short* bSrc = Bt + ((size_t)(nt * 128 + wid * 32 + (lane >> 3))) * KP + (lane & 7) * 8;
    unsigned short* aDst = As + wid * 32 * 64;
    unsigned short* bDst = Bs + wid * 32 * 64;

    for (int kt = 0; kt < KP / 64; ++kt) {
        __syncthreads();
        #pragma unroll
        for (int i = 0; i < 4; ++i) {
            gload16(aSrc + kt * 64 + (size_t)i * 8 * KP, aDst + i * 8 * 64);
            gload16(bSrc + kt * 64 + (size_t)i * 8 * KP, bDst + i * 8 * 64);
        }
        __syncthreads();
        #pragma unroll
        for (int kk = 0; kk < 2; ++kk) {
            bf16x8 af[4], bfr[4];
            int klane = kk * 32 + ((lane >> 4) << 3);
            #pragma unroll
            for (int m = 0; m < 4; ++m) {
                int arow = wm * 64 + m * 16 + (lane & 15);
                af[m] = *(const bf16x8*)&As[arow * 64 + klane];
            }
            #pragma unroll
            for (int n = 0; n < 4; ++n) {
                int brow = wn * 64 + n * 16 + (lane & 15);
                bfr[n] = *(const bf16x8*)&Bs[brow * 64 + klane];
            }
            #pragma unroll
            for (int m = 0; m < 4; ++m)
                #pragma unroll
                for (int n = 0; n < 4; ++n)
                    acc[m][n] = __builtin_amdgcn_mfma_f32_16x16x32_bf16(af[m], bfr[n], acc[m][n], 0, 0, 0);
        }
    }

    // ---- fused epilogue: partials[nt][row][5] = sum_cols relu(acc+b1)*W2 ----
    float w2r[4][5], b1r[4];
    #pragma unroll
    for (int n = 0; n < 4; ++n) {
        int coll = wn * 64 + n * 16 + (lane & 15);
        b1r[n] = b1s[coll];
        #pragma unroll
        for (int j = 0; j < 5; ++j) w2r[n][j] = W2s[coll * 5 + j];
    }
    #pragma unroll
    for (int m = 0; m < 4; ++m) {
        float s[4][5];
        #pragma unroll
        for (int r = 0; r < 4; ++r)
            #pragma unroll
            for (int j = 0; j < 5; ++j) s[r][j] = 0.f;
        #pragma unroll
        for (int n = 0; n < 4; ++n)
            #pragma unroll
            for (int r = 0; r < 4; ++r) {
                float hv = fmaxf(acc[m][n][r] + b1r[n], 0.f);
                #pragma unroll
                for (int j = 0; j < 5; ++j) s[r][j] += hv * w2r[n][j];
            }
        // butterfly within the 16-lane row group (xor bits 0..3)
        #pragma unroll
        for (int o = 1; o < 16; o <<= 1)
            #pragma unroll
            for (int r = 0; r < 4; ++r)
                #pragma unroll
                for (int j = 0; j < 5; ++j) s[r][j] += __shfl_xor(s[r][j], o);
        int lrow = wm * 64 + m * 16 + ((lane >> 4) << 2);
        if (wn == 1 && (lane & 15) == 0) {
            #pragma unroll
            for (int r = 0; r < 4; ++r)
                #pragma unroll
                for (int j = 0; j < 5; ++j) ps[lrow + r][j] = s[r][j];
        }
        __syncthreads();
        if (wn == 0 && (lane & 15) == 0) {
            #pragma unroll
            for (int r = 0; r < 4; ++r) {
                size_t base = ((size_t)nt * B_ROWS + (size_t)(mt * 128) + lrow + r) * 5;
                #pragma unroll
                for (int j = 0; j < 5; ++j)
                    partials[base + j] = s[r][j] + ps[lrow + r][j];
            }
        }
        // no second barrier needed: next m touches disjoint ps rows
    }
}

// ---------------- Kernel 4: reduce partials + b2 ----------------
__global__ __launch_bounds__(256) void k_reduce(const float* __restrict__ partials,
                                                const float* __restrict__ b2,
                                                float* __restrict__ out) {
    int idx = blockIdx.x * 256 + threadIdx.x;
    if (idx >= B_ROWS * 5) return;
    float s = b2[idx % 5];
    #pragma unroll
    for (int t = 0; t < NT_N; ++t) s += partials[(size_t)t * (B_ROWS * 5) + idx];
    out[idx] = s;
}

extern "C" void kernel_launch(void* const* d_in, const int* in_sizes, int n_in,
                              void* d_out, int out_size, void* d_ws, size_t ws_size,
                              hipStream_t stream) {
    const float* h_final   = (const float*)d_in[0];
    const float* v_current = (const float*)d_in[1];
    const float* v_basin   = (const float*)d_in[2];
    const float* W1        = (const float*)d_in[3];
    const float* b1        = (const float*)d_in[4];
    const float* W2        = (const float*)d_in[5];
    const float* b2        = (const float*)d_in[6];
    float* out = (float*)d_out;

    char* ws = (char*)d_ws;
    unsigned short* featpad = (unsigned short*)ws;                       // 16384*1088*2 = 35,651,584 B
    unsigned short* w1t     = (unsigned short*)(ws + 35651584);          // 1152*1088*2  =  2,506,752 B
    float*          parts   = (float*)(ws + 35651584 + 2506752);         // 9*16384*5*4  =  2,949,120 B

    k_vstats<<<dim3(B_ROWS / 4), dim3(256), 0, stream>>>(v_current, v_basin, featpad);
    k_hconv<<<dim3(B_ROWS / 8), dim3(256), 0, stream>>>(h_final, featpad);
    k_w1t<<<dim3((NP * KP + 255) / 256), dim3(256), 0, stream>>>(W1, w1t);
    k_gemm<<<dim3(NT_N * NT_M), dim3(256), 0, stream>>>(featpad, w1t, b1, W2, parts);
    k_reduce<<<dim3((B_ROWS * 5 + 255) / 256), dim3(256), 0, stream>>>(parts, b2, out);
}

// Round 13
// 125.060 us; speedup vs baseline: 1.3259x; 1.1456x over previous
//
#include <hip/hip_runtime.h>
#include <hip/hip_bf16.h>

#define B_ROWS 16384
#define D_DIM  1024
#define F_DIM  1031
#define KP     1088   // padded K (17 * 64)
#define NP     1152   // padded N / hidden stride (9 * 128)
#define NT_N   9
#define NT_M   128

typedef __attribute__((ext_vector_type(4))) float  f32x4;
typedef __attribute__((ext_vector_type(8))) short  bf16x8;

__device__ __forceinline__ unsigned short f2bf(float f) {
    unsigned int x = __float_as_uint(f);
    unsigned int r = (x + 0x7fffu + ((x >> 16) & 1u)) >> 16;
    return (unsigned short)r;
}
__device__ __forceinline__ float bf2f(unsigned short u) {
    return __uint_as_float((unsigned int)u << 16);
}
__device__ __forceinline__ void gload16(const void* g, void* l) {
    __builtin_amdgcn_global_load_lds(
        (const __attribute__((address_space(1))) void*)g,
        (__attribute__((address_space(3))) void*)l, 16, 0, 0);
}

// Swizzle convention (rule #21 involution, baked into GLOBAL contents):
//   stored[row][c] = logical[row][(c & ~63) + ((c & 63) ^ ((row & 7) << 3))]
// global_load_lds stays linear; ds_read XORs the byte offset with ((row&7)<<4).

// ---------------- Kernel 1a: vc/vb stats (wave = 1 row) ---------------
__global__ __launch_bounds__(256) void k_vstats(
        const float* __restrict__ vc, const float* __restrict__ vb,
        unsigned short* __restrict__ featpad) {
    int tid  = threadIdx.x;
    int lane = tid & 63;
    int row  = blockIdx.x * 4 + (tid >> 6);

    const float4* c4 = (const float4*)(vc + (size_t)row * D_DIM);
    const float4* b4 = (const float4*)(vb + (size_t)row * D_DIM);

    float4 cv[4], bv[4];
    #pragma unroll
    for (int b = 0; b < 4; ++b) { cv[b] = c4[lane + 64 * b]; bv[b] = b4[lane + 64 * b]; }

    float nc = 0.f, nb = 0.f, dcb = 0.f;
    #pragma unroll
    for (int b = 0; b < 4; ++b) {
        nc  += cv[b].x*cv[b].x + cv[b].y*cv[b].y + cv[b].z*cv[b].z + cv[b].w*cv[b].w;
        nb  += bv[b].x*bv[b].x + bv[b].y*bv[b].y + bv[b].z*bv[b].z + bv[b].w*bv[b].w;
        dcb += cv[b].x*bv[b].x + cv[b].y*bv[b].y + cv[b].z*bv[b].z + cv[b].w*bv[b].w;
    }
    #pragma unroll
    for (int o = 1; o < 64; o <<= 1) {
        nc  += __shfl_xor(nc,  o);
        nb  += __shfl_xor(nb,  o);
        dcb += __shfl_xor(dcb, o);
    }

    float rc = sqrtf(nc), rb = sqrtf(nb);
    float mc = fmaxf(rc, 1e-12f), mb = fmaxf(rb, 1e-12f);
    float align = dcb / (mc * mb);
    float t2 = nc/(mc*mc) - 2.f*dcb/(mc*mb) + nb/(mb*mb);
    t2 = fmaxf(t2, 0.f);
    float scal[6];
    scal[0] = align;
    scal[1] = sqrtf(t2);
    scal[2] = t2;
    scal[3] = sqrtf(fmaxf(nc - 2.f*dcb + nb, 0.f));
    scal[4] = rc; scal[5] = rb;

    // tail block (storage cols 1024..1087, swizzled): storage col 1024+lane holds
    // logical col 1024 + (lane ^ s). Skip logical 1030 (r_final from k_hconv).
    int s = (row & 7) << 3;
    int lc = lane ^ s;
    unsigned short* orow = featpad + (size_t)row * KP;
    if (lc != 6) {
        float v = (lc < 6) ? scal[lc] : 0.f;
        orow[1024 + lane] = f2bf(v);
    }
}

// ---------------- Kernel 1b: h -> swizzled bf16 + r_final (wave = 2 rows) ------------
__global__ __launch_bounds__(256) void k_hconv(
        const float* __restrict__ h, unsigned short* __restrict__ featpad) {
    int tid  = threadIdx.x;
    int lane = tid & 63;
    int row0 = blockIdx.x * 8 + (tid >> 6) * 2;

    const float4* h40 = (const float4*)(h + (size_t)row0 * D_DIM);
    const float4* h41 = (const float4*)(h + (size_t)(row0 + 1) * D_DIM);

    float4 hv0[4], hv1[4];
    #pragma unroll
    for (int b = 0; b < 4; ++b) { hv0[b] = h40[lane + 64 * b]; hv1[b] = h41[lane + 64 * b]; }

    float nh0 = 0.f, nh1 = 0.f;
    #pragma unroll
    for (int b = 0; b < 4; ++b) {
        nh0 += hv0[b].x*hv0[b].x + hv0[b].y*hv0[b].y + hv0[b].z*hv0[b].z + hv0[b].w*hv0[b].w;
        nh1 += hv1[b].x*hv1[b].x + hv1[b].y*hv1[b].y + hv1[b].z*hv1[b].z + hv1[b].w*hv1[b].w;
    }
    #pragma unroll
    for (int o = 1; o < 64; o <<= 1) {
        nh0 += __shfl_xor(nh0, o);
        nh1 += __shfl_xor(nh1, o);
    }

    int s0 = (row0 & 7) << 3;
    int s1 = ((row0 + 1) & 7) << 3;
    unsigned short* orow0 = featpad + (size_t)row0 * KP;
    unsigned short* orow1 = orow0 + KP;
    // lane holds logical cols c0..c0+3 (c0 = 4*(lane+64b)); store at swizzled position.
    // XOR touches only bits 3-5 of (c&63), so a 4-element group stays contiguous.
    #pragma unroll
    for (int b = 0; b < 4; ++b) {
        int c0 = 4 * (lane + 64 * b);
        int st0 = (c0 & ~63) + ((c0 & 63) ^ s0);
        int st1 = (c0 & ~63) + ((c0 & 63) ^ s1);
        union { unsigned int u[2]; unsigned short us[4]; } w0, w1;
        w0.us[0] = f2bf(hv0[b].x); w0.us[1] = f2bf(hv0[b].y);
        w0.us[2] = f2bf(hv0[b].z); w0.us[3] = f2bf(hv0[b].w);
        w1.us[0] = f2bf(hv1[b].x); w1.us[1] = f2bf(hv1[b].y);
        w1.us[2] = f2bf(hv1[b].z); w1.us[3] = f2bf(hv1[b].w);
        *(uint2*)(orow0 + st0) = *(uint2*)w0.u;
        *(uint2*)(orow1 + st1) = *(uint2*)w1.u;
    }
    if (lane == 0) orow0[1024 + (6 ^ s0)] = f2bf(sqrtf(nh0));
    if (lane == 1) orow1[1024 + (6 ^ s1)] = f2bf(sqrtf(nh1));
}

// ---------------- Kernel 2: W1 -> W1^T bf16, padded, swizzled ----------------
__global__ __launch_bounds__(256) void k_w1t(const float* __restrict__ W1,
                                             unsigned short* __restrict__ w1t) {
    int idx = blockIdx.x * 256 + threadIdx.x;
    if (idx >= NP * KP) return;
    int n = idx / KP, c = idx % KP;
    int s = (n & 7) << 3;
    int src_k = (c & ~63) + ((c & 63) ^ s);
    float v = 0.f;
    if (n < F_DIM && src_k < F_DIM) v = W1[(size_t)src_k * F_DIM + n];
    w1t[idx] = f2bf(v);
}

// ---------------- Kernel 3: GEMM1 (+b1, ReLU) -> bf16 hidden --------------------------
// r10-exact structure (single-buffer 2-barrier, global_load_lds linear) + swizzled
// ds_read addresses (conflict-free: 2-way residual aliasing only).
__global__ __launch_bounds__(256, 1) void k_gemm(
        const unsigned short* __restrict__ A,   // featpad [16384][1088] (swizzled)
        const unsigned short* __restrict__ Bt,  // w1t [1152][1088] (swizzled)
        const float* __restrict__ b1,
        unsigned short* __restrict__ hidden) {  // [16384][1152] linear
    __shared__ unsigned short As[128 * 64];   // 16 KB, linear
    __shared__ unsigned short Bs[128 * 64];   // 16 KB, linear
    __shared__ float b1s[128];

    int tid = threadIdx.x;
    int lane = tid & 63;
    int wid = tid >> 6;

    // XCD-aware mapping (bijective): 9 nt-blocks per A panel on one XCD.
    int id = blockIdx.x;            // 0..1151
    int xcd = id & 7;
    int slot = id >> 3;             // 0..143
    int mt = xcd * 16 + slot / NT_N;
    int nt = slot % NT_N;

    if (tid < 128) {
        int ncol = nt * 128 + tid;
        b1s[tid] = (ncol < F_DIM) ? b1[ncol] : 0.f;
    }

    f32x4 acc[4][4] = {};
    int wm = wid >> 1, wn = wid & 1;

    const unsigned short* aSrc = A  + ((size_t)(mt * 128 + wid * 32 + (lane >> 3))) * KP + (lane & 7) * 8;
    const unsigned short* bSrc = Bt + ((size_t)(nt * 128 + wid * 32 + (lane >> 3))) * KP + (lane & 7) * 8;
    unsigned short* aDst = As + wid * 32 * 64;
    unsigned short* bDst = Bs + wid * 32 * 64;

    for (int kt = 0; kt < KP / 64; ++kt) {
        __syncthreads();
        #pragma unroll
        for (int i = 0; i < 4; ++i) {
            gload16(aSrc + kt * 64 + (size_t)i * 8 * KP, aDst + i * 8 * 64);
            gload16(bSrc + kt * 64 + (size_t)i * 8 * KP, bDst + i * 8 * 64);
        }
        __syncthreads();
        #pragma unroll
        for (int kk = 0; kk < 2; ++kk) {
            bf16x8 af[4], bfr[4];
            int klane = kk * 32 + ((lane >> 4) << 3);
            #pragma unroll
            for (int m = 0; m < 4; ++m) {
                int arow = wm * 64 + m * 16 + (lane & 15);
                int abyte = arow * 128 + ((klane * 2) ^ ((arow & 7) << 4));
                af[m] = *(const bf16x8*)((const char*)As + abyte);
            }
            #pragma unroll
            for (int n = 0; n < 4; ++n) {
                int brow = wn * 64 + n * 16 + (lane & 15);
                int bbyte = brow * 128 + ((klane * 2) ^ ((brow & 7) << 4));
                bfr[n] = *(const bf16x8*)((const char*)Bs + bbyte);
            }
            #pragma unroll
            for (int m = 0; m < 4; ++m)
                #pragma unroll
                for (int n = 0; n < 4; ++n)
                    acc[m][n] = __builtin_amdgcn_mfma_f32_16x16x32_bf16(af[m], bfr[n], acc[m][n], 0, 0, 0);
        }
    }

    #pragma unroll
    for (int m = 0; m < 4; ++m) {
        #pragma unroll
        for (int n = 0; n < 4; ++n) {
            int coll = wn * 64 + n * 16 + (lane & 15);
            int col = nt * 128 + coll;
            #pragma unroll
            for (int r = 0; r < 4; ++r) {
                int row = mt * 128 + wm * 64 + m * 16 + ((lane >> 4) << 2) + r;
                float v = acc[m][n][r] + b1s[coll];
                hidden[(size_t)row * NP + col] = f2bf(fmaxf(v, 0.f));
            }
        }
    }
}

// ---------------- Kernel 4: out = hidden @ W2 + b2 (memory-bound stream) -------------
__global__ __launch_bounds__(256) void k_head(const unsigned short* __restrict__ hidden,
                                              const float* __restrict__ W2,
                                              const float* __restrict__ b2,
                                              float* __restrict__ out) {
    __shared__ float W2s[NP * 5];   // 23,040 B
    int tid = threadIdx.x;
    for (int idx = tid; idx < NP * 5; idx += 256) {
        int n = idx / 5, j = idx % 5;
        W2s[idx] = (n < F_DIM) ? W2[n * 5 + j] : 0.f;
    }
    __syncthreads();

    int wid = tid >> 6, lane = tid & 63;
    int row = blockIdx.x * 16 + wid * 4 + (lane >> 4);   // 16 rows/block
    int seg = lane & 15;                                  // 16 lanes per row, 72 cols each
    const unsigned short* hr = hidden + (size_t)row * NP + seg * 72;

    float s[5] = {0.f, 0.f, 0.f, 0.f, 0.f};
    #pragma unroll
    for (int c = 0; c < 9; ++c) {
        union { uint4 v; unsigned short us[8]; } pk;
        pk.v = *(const uint4*)(hr + c * 8);
        #pragma unroll
        for (int e = 0; e < 8; ++e) {
            float hv = bf2f(pk.us[e]);
            int col = seg * 72 + c * 8 + e;
            #pragma unroll
            for (int j = 0; j < 5; ++j) s[j] += hv * W2s[col * 5 + j];
        }
    }
    #pragma unroll
    for (int o = 1; o < 16; o <<= 1) {
        #pragma unroll
        for (int j = 0; j < 5; ++j) s[j] += __shfl_xor(s[j], o);
    }
    if (seg == 0) {
        #pragma unroll
        for (int j = 0; j < 5; ++j) out[(size_t)row * 5 + j] = s[j] + b2[j];
    }
}

extern "C" void kernel_launch(void* const* d_in, const int* in_sizes, int n_in,
                              void* d_out, int out_size, void* d_ws, size_t ws_size,
                              hipStream_t stream) {
    const float* h_final   = (const float*)d_in[0];
    const float* v_current = (const float*)d_in[1];
    const float* v_basin   = (const float*)d_in[2];
    const float* W1        = (const float*)d_in[3];
    const float* b1        = (const float*)d_in[4];
    const float* W2        = (const float*)d_in[5];
    const float* b2        = (const float*)d_in[6];
    float* out = (float*)d_out;

    char* ws = (char*)d_ws;
    unsigned short* featpad = (unsigned short*)ws;                       // 16384*1088*2 = 35,651,584 B
    unsigned short* w1t     = (unsigned short*)(ws + 35651584);          // 1152*1088*2  =  2,506,752 B
    unsigned short* hidden  = (unsigned short*)(ws + 35651584 + 2506752);// 16384*1152*2 = 37,748,736 B

    k_vstats<<<dim3(B_ROWS / 4), dim3(256), 0, stream>>>(v_current, v_basin, featpad);
    k_hconv<<<dim3(B_ROWS / 8), dim3(256), 0, stream>>>(h_final, featpad);
    k_w1t<<<dim3((NP * KP + 255) / 256), dim3(256), 0, stream>>>(W1, w1t);
    k_gemm<<<dim3(NT_N * NT_M), dim3(256), 0, stream>>>(featpad, w1t, b1, hidden);
    k_head<<<dim3(B_ROWS / 16), dim3(256), 0, stream>>>(hidden, W2, b2, out);
}

// Round 14
// 116.224 us; speedup vs baseline: 1.4267x; 1.0760x over previous
//
#include <hip/hip_runtime.h>
#include <hip/hip_bf16.h>

#define B_ROWS 16384
#define D_DIM  1024
#define F_DIM  1031
#define KP     1088   // padded K (17 * 64)
#define NP     1152   // padded N / hidden stride (9 * 128)
#define NT_N   9
#define NT_M   128

// k_prep grid layout
#define NB_VSTATS (B_ROWS / 4)                  // 4096
#define NB_HCONV  (B_ROWS / 8)                  // 2048
#define NB_W1T    ((NP * KP + 255) / 256)       // 4896

typedef __attribute__((ext_vector_type(4))) float  f32x4;
typedef __attribute__((ext_vector_type(8))) short  bf16x8;

__device__ __forceinline__ unsigned short f2bf(float f) {
    unsigned int x = __float_as_uint(f);
    unsigned int r = (x + 0x7fffu + ((x >> 16) & 1u)) >> 16;
    return (unsigned short)r;
}
__device__ __forceinline__ float bf2f(unsigned short u) {
    return __uint_as_float((unsigned int)u << 16);
}
__device__ __forceinline__ void gload16(const void* g, void* l) {
    __builtin_amdgcn_global_load_lds(
        (const __attribute__((address_space(1))) void*)g,
        (__attribute__((address_space(3))) void*)l, 16, 0, 0);
}

// Swizzle convention (baked into GLOBAL contents of featpad/w1t):
//   stored[row][c] = logical[row][(c & ~63) + ((c & 63) ^ ((row & 7) << 3))]
// global_load_lds stays linear; ds_read XORs the byte offset with ((row&7)<<4).

__device__ __forceinline__ void prep_vstats(int bid,
        const float* __restrict__ vc, const float* __restrict__ vb,
        unsigned short* __restrict__ featpad) {
    int tid  = threadIdx.x;
    int lane = tid & 63;
    int row  = bid * 4 + (tid >> 6);

    const float4* c4 = (const float4*)(vc + (size_t)row * D_DIM);
    const float4* b4 = (const float4*)(vb + (size_t)row * D_DIM);

    float4 cv[4], bv[4];
    #pragma unroll
    for (int b = 0; b < 4; ++b) { cv[b] = c4[lane + 64 * b]; bv[b] = b4[lane + 64 * b]; }

    float nc = 0.f, nb = 0.f, dcb = 0.f;
    #pragma unroll
    for (int b = 0; b < 4; ++b) {
        nc  += cv[b].x*cv[b].x + cv[b].y*cv[b].y + cv[b].z*cv[b].z + cv[b].w*cv[b].w;
        nb  += bv[b].x*bv[b].x + bv[b].y*bv[b].y + bv[b].z*bv[b].z + bv[b].w*bv[b].w;
        dcb += cv[b].x*bv[b].x + cv[b].y*bv[b].y + cv[b].z*bv[b].z + cv[b].w*bv[b].w;
    }
    #pragma unroll
    for (int o = 1; o < 64; o <<= 1) {
        nc  += __shfl_xor(nc,  o);
        nb  += __shfl_xor(nb,  o);
        dcb += __shfl_xor(dcb, o);
    }

    float rc = sqrtf(nc), rb = sqrtf(nb);
    float mc = fmaxf(rc, 1e-12f), mb = fmaxf(rb, 1e-12f);
    float align = dcb / (mc * mb);
    float t2 = nc/(mc*mc) - 2.f*dcb/(mc*mb) + nb/(mb*mb);
    t2 = fmaxf(t2, 0.f);
    float scal[6];
    scal[0] = align;
    scal[1] = sqrtf(t2);
    scal[2] = t2;
    scal[3] = sqrtf(fmaxf(nc - 2.f*dcb + nb, 0.f));
    scal[4] = rc; scal[5] = rb;

    int s = (row & 7) << 3;
    int lc = lane ^ s;
    unsigned short* orow = featpad + (size_t)row * KP;
    if (lc != 6) {
        float v = (lc < 6) ? scal[lc] : 0.f;
        orow[1024 + lane] = f2bf(v);
    }
}

__device__ __forceinline__ void prep_hconv(int bid,
        const float* __restrict__ h, unsigned short* __restrict__ featpad) {
    int tid  = threadIdx.x;
    int lane = tid & 63;
    int row0 = bid * 8 + (tid >> 6) * 2;

    const float4* h40 = (const float4*)(h + (size_t)row0 * D_DIM);
    const float4* h41 = (const float4*)(h + (size_t)(row0 + 1) * D_DIM);

    float4 hv0[4], hv1[4];
    #pragma unroll
    for (int b = 0; b < 4; ++b) { hv0[b] = h40[lane + 64 * b]; hv1[b] = h41[lane + 64 * b]; }

    float nh0 = 0.f, nh1 = 0.f;
    #pragma unroll
    for (int b = 0; b < 4; ++b) {
        nh0 += hv0[b].x*hv0[b].x + hv0[b].y*hv0[b].y + hv0[b].z*hv0[b].z + hv0[b].w*hv0[b].w;
        nh1 += hv1[b].x*hv1[b].x + hv1[b].y*hv1[b].y + hv1[b].z*hv1[b].z + hv1[b].w*hv1[b].w;
    }
    #pragma unroll
    for (int o = 1; o < 64; o <<= 1) {
        nh0 += __shfl_xor(nh0, o);
        nh1 += __shfl_xor(nh1, o);
    }

    int s0 = (row0 & 7) << 3;
    int s1 = ((row0 + 1) & 7) << 3;
    unsigned short* orow0 = featpad + (size_t)row0 * KP;
    unsigned short* orow1 = orow0 + KP;
    #pragma unroll
    for (int b = 0; b < 4; ++b) {
        int c0 = 4 * (lane + 64 * b);
        int st0 = (c0 & ~63) + ((c0 & 63) ^ s0);
        int st1 = (c0 & ~63) + ((c0 & 63) ^ s1);
        union { unsigned int u[2]; unsigned short us[4]; } w0, w1;
        w0.us[0] = f2bf(hv0[b].x); w0.us[1] = f2bf(hv0[b].y);
        w0.us[2] = f2bf(hv0[b].z); w0.us[3] = f2bf(hv0[b].w);
        w1.us[0] = f2bf(hv1[b].x); w1.us[1] = f2bf(hv1[b].y);
        w1.us[2] = f2bf(hv1[b].z); w1.us[3] = f2bf(hv1[b].w);
        *(uint2*)(orow0 + st0) = *(uint2*)w0.u;
        *(uint2*)(orow1 + st1) = *(uint2*)w1.u;
    }
    if (lane == 0) orow0[1024 + (6 ^ s0)] = f2bf(sqrtf(nh0));
    if (lane == 1) orow1[1024 + (6 ^ s1)] = f2bf(sqrtf(nh1));
}

__device__ __forceinline__ void prep_w1t(int bid,
        const float* __restrict__ W1, unsigned short* __restrict__ w1t) {
    int idx = bid * 256 + threadIdx.x;
    if (idx >= NP * KP) return;
    int n = idx / KP, c = idx % KP;
    int s = (n & 7) << 3;
    int src_k = (c & ~63) + ((c & 63) ^ s);
    float v = 0.f;
    if (n < F_DIM && src_k < F_DIM) v = W1[(size_t)src_k * F_DIM + n];
    w1t[idx] = f2bf(v);
}

// ---------------- Kernel 1: fused prep (vstats | hconv | w1t by block range) ----------
__global__ __launch_bounds__(256) void k_prep(
        const float* __restrict__ h, const float* __restrict__ vc,
        const float* __restrict__ vb, const float* __restrict__ W1,
        unsigned short* __restrict__ featpad, unsigned short* __restrict__ w1t) {
    int bid = blockIdx.x;
    if (bid < NB_VSTATS) {
        prep_vstats(bid, vc, vb, featpad);
    } else if (bid < NB_VSTATS + NB_HCONV) {
        prep_hconv(bid - NB_VSTATS, h, featpad);
    } else {
        prep_w1t(bid - NB_VSTATS - NB_HCONV, W1, w1t);
    }
}

// ---------------- Kernel 2: GEMM1 (+b1, ReLU) -> bf16 hidden --------------------------
// r13-exact structure; __launch_bounds__ min-waves 1 -> 4 (VGPR 84 well under 128 cap).
__global__ __launch_bounds__(256, 4) void k_gemm(
        const unsigned short* __restrict__ A,   // featpad [16384][1088] (swizzled)
        const unsigned short* __restrict__ Bt,  // w1t [1152][1088] (swizzled)
        const float* __restrict__ b1,
        unsigned short* __restrict__ hidden) {  // [16384][1152] linear
    __shared__ unsigned short As[128 * 64];   // 16 KB, linear
    __shared__ unsigned short Bs[128 * 64];   // 16 KB, linear
    __shared__ float b1s[128];

    int tid = threadIdx.x;
    int lane = tid & 63;
    int wid = tid >> 6;

    // XCD-aware mapping (bijective): 9 nt-blocks per A panel on one XCD.
    int id = blockIdx.x;            // 0..1151
    int xcd = id & 7;
    int slot = id >> 3;             // 0..143
    int mt = xcd * 16 + slot / NT_N;
    int nt = slot % NT_N;

    if (tid < 128) {
        int ncol = nt * 128 + tid;
        b1s[tid] = (ncol < F_DIM) ? b1[ncol] : 0.f;
    }

    f32x4 acc[4][4] = {};
    int wm = wid >> 1, wn = wid & 1;

    const unsigned short* aSrc = A  + ((size_t)(mt * 128 + wid * 32 + (lane >> 3))) * KP + (lane & 7) * 8;
    const unsigned short* bSrc = Bt + ((size_t)(nt * 128 + wid * 32 + (lane >> 3))) * KP + (lane & 7) * 8;
    unsigned short* aDst = As + wid * 32 * 64;
    unsigned short* bDst = Bs + wid * 32 * 64;

    for (int kt = 0; kt < KP / 64; ++kt) {
        __syncthreads();
        #pragma unroll
        for (int i = 0; i < 4; ++i) {
            gload16(aSrc + kt * 64 + (size_t)i * 8 * KP, aDst + i * 8 * 64);
            gload16(bSrc + kt * 64 + (size_t)i * 8 * KP, bDst + i * 8 * 64);
        }
        __syncthreads();
        #pragma unroll
        for (int kk = 0; kk < 2; ++kk) {
            bf16x8 af[4], bfr[4];
            int klane = kk * 32 + ((lane >> 4) << 3);
            #pragma unroll
            for (int m = 0; m < 4; ++m) {
                int arow = wm * 64 + m * 16 + (lane & 15);
                int abyte = arow * 128 + ((klane * 2) ^ ((arow & 7) << 4));
                af[m] = *(const bf16x8*)((const char*)As + abyte);
            }
            #pragma unroll
            for (int n = 0; n < 4; ++n) {
                int brow = wn * 64 + n * 16 + (lane & 15);
                int bbyte = brow * 128 + ((klane * 2) ^ ((brow & 7) << 4));
                bfr[n] = *(const bf16x8*)((const char*)Bs + bbyte);
            }
            #pragma unroll
            for (int m = 0; m < 4; ++m)
                #pragma unroll
                for (int n = 0; n < 4; ++n)
                    acc[m][n] = __builtin_amdgcn_mfma_f32_16x16x32_bf16(af[m], bfr[n], acc[m][n], 0, 0, 0);
        }
    }

    #pragma unroll
    for (int m = 0; m < 4; ++m) {
        #pragma unroll
        for (int n = 0; n < 4; ++n) {
            int coll = wn * 64 + n * 16 + (lane & 15);
            int col = nt * 128 + coll;
            #pragma unroll
            for (int r = 0; r < 4; ++r) {
                int row = mt * 128 + wm * 64 + m * 16 + ((lane >> 4) << 2) + r;
                float v = acc[m][n][r] + b1s[coll];
                hidden[(size_t)row * NP + col] = f2bf(fmaxf(v, 0.f));
            }
        }
    }
}

// ---------------- Kernel 3: out = hidden @ W2 + b2 (memory-bound stream) -------------
__global__ __launch_bounds__(256) void k_head(const unsigned short* __restrict__ hidden,
                                              const float* __restrict__ W2,
                                              const float* __restrict__ b2,
                                              float* __restrict__ out) {
    __shared__ float W2s[NP * 5];   // 23,040 B
    int tid = threadIdx.x;
    for (int idx = tid; idx < NP * 5; idx += 256) {
        int n = idx / 5, j = idx % 5;
        W2s[idx] = (n < F_DIM) ? W2[n * 5 + j] : 0.f;
    }
    __syncthreads();

    int wid = tid >> 6, lane = tid & 63;
    int row = blockIdx.x * 16 + wid * 4 + (lane >> 4);   // 16 rows/block
    int seg = lane & 15;                                  // 16 lanes per row, 72 cols each
    const unsigned short* hr = hidden + (size_t)row * NP + seg * 72;

    float s[5] = {0.f, 0.f, 0.f, 0.f, 0.f};
    #pragma unroll
    for (int c = 0; c < 9; ++c) {
        union { uint4 v; unsigned short us[8]; } pk;
        pk.v = *(const uint4*)(hr + c * 8);
        #pragma unroll
        for (int e = 0; e < 8; ++e) {
            float hv = bf2f(pk.us[e]);
            int col = seg * 72 + c * 8 + e;
            #pragma unroll
            for (int j = 0; j < 5; ++j) s[j] += hv * W2s[col * 5 + j];
        }
    }
    #pragma unroll
    for (int o = 1; o < 16; o <<= 1) {
        #pragma unroll
        for (int j = 0; j < 5; ++j) s[j] += __shfl_xor(s[j], o);
    }
    if (seg == 0) {
        #pragma unroll
        for (int j = 0; j < 5; ++j) out[(size_t)row * 5 + j] = s[j] + b2[j];
    }
}

extern "C" void kernel_launch(void* const* d_in, const int* in_sizes, int n_in,
                              void* d_out, int out_size, void* d_ws, size_t ws_size,
                              hipStream_t stream) {
    const float* h_final   = (const float*)d_in[0];
    const float* v_current = (const float*)d_in[1];
    const float* v_basin   = (const float*)d_in[2];
    const float* W1        = (const float*)d_in[3];
    const float* b1        = (const float*)d_in[4];
    const float* W2        = (const float*)d_in[5];
    const float* b2        = (const float*)d_in[6];
    float* out = (float*)d_out;

    char* ws = (char*)d_ws;
    unsigned short* featpad = (unsigned short*)ws;                       // 16384*1088*2 = 35,651,584 B
    unsigned short* w1t     = (unsigned short*)(ws + 35651584);          // 1152*1088*2  =  2,506,752 B
    unsigned short* hidden  = (unsigned short*)(ws + 35651584 + 2506752);// 16384*1152*2 = 37,748,736 B

    k_prep<<<dim3(NB_VSTATS + NB_HCONV + NB_W1T), dim3(256), 0, stream>>>(
        h_final, v_current, v_basin, W1, featpad, w1t);
    k_gemm<<<dim3(NT_N * NT_M), dim3(256), 0, stream>>>(featpad, w1t, b1, hidden);
    k_head<<<dim3(B_ROWS / 16), dim3(256), 0, stream>>>(hidden, W2, b2, out);
}

// Round 15
// 113.129 us; speedup vs baseline: 1.4658x; 1.0274x over previous
//
#include <hip/hip_runtime.h>
#include <hip/hip_bf16.h>

#define B_ROWS 16384
#define D_DIM  1024
#define F_DIM  1031
#define KP     1088   // padded K (17 * 64)
#define NP     1152   // padded N / hidden stride (9 * 128)
#define NT_N   9
#define NT_M   128

// k_prep grid layout
#define NB_VSTATS (B_ROWS / 4)                  // 4096 (4 rows/block)
#define NB_HCONV  (B_ROWS / 8)                  // 2048 (8 rows/block)
#define NB_W1T    ((NP / 64) * (KP / 64))       // 18*17 = 306 (64x64 tiles)

typedef __attribute__((ext_vector_type(4))) float  f32x4;
typedef __attribute__((ext_vector_type(8))) short  bf16x8;

__device__ __forceinline__ unsigned short f2bf(float f) {
    unsigned int x = __float_as_uint(f);
    unsigned int r = (x + 0x7fffu + ((x >> 16) & 1u)) >> 16;
    return (unsigned short)r;
}
__device__ __forceinline__ float bf2f(unsigned short u) {
    return __uint_as_float((unsigned int)u << 16);
}
__device__ __forceinline__ void gload16(const void* g, void* l) {
    __builtin_amdgcn_global_load_lds(
        (const __attribute__((address_space(1))) void*)g,
        (__attribute__((address_space(3))) void*)l, 16, 0, 0);
}

// Swizzle convention (baked into GLOBAL contents of featpad/w1t):
//   stored[row][c] = logical[row][(c & ~63) + ((c & 63) ^ ((row & 7) << 3))]
// gemm's global_load_lds stays linear; its ds_read XORs byte offset with ((row&7)<<4).

// ---- vstats: 4 rows; stage vc+vb (32 KB) via gload16, wave w reduces row w ----------
__device__ __forceinline__ void prep_vstats(int bid, char* smem,
        const float* __restrict__ vc, const float* __restrict__ vb,
        unsigned short* __restrict__ featpad) {
    int tid = threadIdx.x, lane = tid & 63, wid = tid >> 6;
    int row0 = bid * 4;

    // stage: call r covers row r (4 KB); per-wave dst base = r*4096 + wid*1024
    #pragma unroll
    for (int r = 0; r < 4; ++r) {
        gload16(vc + (size_t)(row0 + r) * D_DIM + tid * 4, smem + r * 4096 + wid * 1024);
        gload16(vb + (size_t)(row0 + r) * D_DIM + tid * 4, smem + 16384 + r * 4096 + wid * 1024);
    }
    __syncthreads();

    int row = row0 + wid;
    const char* cbase = smem + wid * 4096;
    const char* bbase = smem + 16384 + wid * 4096;
    float nc = 0.f, nb = 0.f, dcb = 0.f;
    #pragma unroll
    for (int i = 0; i < 4; ++i) {
        float4 cv = *(const float4*)(cbase + i * 1024 + lane * 16);
        float4 bv = *(const float4*)(bbase + i * 1024 + lane * 16);
        nc  += cv.x*cv.x + cv.y*cv.y + cv.z*cv.z + cv.w*cv.w;
        nb  += bv.x*bv.x + bv.y*bv.y + bv.z*bv.z + bv.w*bv.w;
        dcb += cv.x*bv.x + cv.y*bv.y + cv.z*bv.z + cv.w*bv.w;
    }
    #pragma unroll
    for (int o = 1; o < 64; o <<= 1) {
        nc  += __shfl_xor(nc,  o);
        nb  += __shfl_xor(nb,  o);
        dcb += __shfl_xor(dcb, o);
    }

    float rc = sqrtf(nc), rb = sqrtf(nb);
    float mc = fmaxf(rc, 1e-12f), mb = fmaxf(rb, 1e-12f);
    float align = dcb / (mc * mb);
    float t2 = nc/(mc*mc) - 2.f*dcb/(mc*mb) + nb/(mb*mb);
    t2 = fmaxf(t2, 0.f);
    float scal[6];
    scal[0] = align;
    scal[1] = sqrtf(t2);
    scal[2] = t2;
    scal[3] = sqrtf(fmaxf(nc - 2.f*dcb + nb, 0.f));
    scal[4] = rc; scal[5] = rb;

    int s = (row & 7) << 3;
    int lc = lane ^ s;
    unsigned short* orow = featpad + (size_t)row * KP;
    if (lc != 6) {
        float v = (lc < 6) ? scal[lc] : 0.f;
        orow[1024 + lane] = f2bf(v);
    }
}

// ---- hconv: 8 rows; stage h (32 KB); wave w: rows 2w,2w+1 (32 lanes each) -----------
__device__ __forceinline__ void prep_hconv(int bid, char* smem,
        const float* __restrict__ h, unsigned short* __restrict__ featpad) {
    int tid = threadIdx.x, lane = tid & 63, wid = tid >> 6;
    int row0 = bid * 8;

    #pragma unroll
    for (int r = 0; r < 8; ++r)
        gload16(h + (size_t)(row0 + r) * D_DIM + tid * 4, smem + r * 4096 + wid * 1024);
    __syncthreads();

    int rowsel = lane >> 5;            // 0/1
    int lane32 = lane & 31;
    int row = row0 + wid * 2 + rowsel;
    int s = (row & 7) << 3;
    const char* hbase = smem + (size_t)(wid * 2 + rowsel) * 4096;
    unsigned short* orow = featpad + (size_t)row * KP;

    float nh = 0.f;
    #pragma unroll
    for (int i = 0; i < 8; ++i) {
        float4 hv = *(const float4*)(hbase + (i * 32 + lane32) * 16);
        nh += hv.x*hv.x + hv.y*hv.y + hv.z*hv.z + hv.w*hv.w;
        union { unsigned int u[2]; unsigned short us[4]; } w;
        w.us[0] = f2bf(hv.x); w.us[1] = f2bf(hv.y);
        w.us[2] = f2bf(hv.z); w.us[3] = f2bf(hv.w);
        int c0 = i * 128 + lane32 * 4;
        int st = (c0 & ~63) | ((c0 & 63) ^ s);
        *(uint2*)(orow + st) = *(uint2*)w.u;
    }
    #pragma unroll
    for (int o = 1; o < 32; o <<= 1) nh += __shfl_xor(nh, o);
    if (lane32 == 0) orow[1024 + (6 ^ s)] = f2bf(sqrtf(nh));
}

// ---- w1t: 64x64 tile; stage W1 rows coalesced (16 KB), transpose-read, swizzle-store -
__device__ __forceinline__ void prep_w1t(int bid, char* smem,
        const float* __restrict__ W1, unsigned short* __restrict__ w1t) {
    int tid = threadIdx.x, wid = tid >> 6;
    int tn = bid / (KP / 64), tk = bid % (KP / 64);
    int n0 = tn * 64, k0 = tk * 64;

    // stage: lds[k_local][n_local] fp32 linear [64][64]; call j covers 16 k-rows
    const size_t lim = (size_t)F_DIM * F_DIM;
    #pragma unroll
    for (int j = 0; j < 4; ++j) {
        int krow = k0 + j * 16 + (tid >> 4);
        size_t li = (size_t)krow * F_DIM + n0 + (tid & 15) * 4;
        if (li + 4 > lim) li = 0;   // clamp in-bounds; garbage masked at write
        gload16(W1 + li, smem + j * 4096 + wid * 1024);
    }
    __syncthreads();

    int n_local = tid >> 2, chunk = tid & 3;
    int n = n0 + n_local;
    int s = (n & 7) << 3;
    const float* lds = (const float*)smem;
    union { uint4 v[2]; unsigned short us[16]; } pk;
    #pragma unroll
    for (int i = 0; i < 16; ++i) {
        int c_local = chunk * 16 + i;
        int src_k = k0 + (c_local ^ s);
        float v = 0.f;
        if (n < F_DIM && src_k < F_DIM) v = lds[(size_t)(c_local ^ s) * 64 + n_local];
        pk.us[i] = f2bf(v);
    }
    unsigned short* orow = w1t + (size_t)n * KP + k0 + chunk * 16;
    *(uint4*)orow = pk.v[0];
    *(uint4*)(orow + 8) = pk.v[1];
}

// ---------------- Kernel 1: fused prep (vstats | hconv | w1t by block range) ----------
__global__ __launch_bounds__(256) void k_prep(
        const float* __restrict__ h, const float* __restrict__ vc,
        const float* __restrict__ vb, const float* __restrict__ W1,
        unsigned short* __restrict__ featpad, unsigned short* __restrict__ w1t) {
    __shared__ __align__(16) char smem[32768];
    int bid = blockIdx.x;
    if (bid < NB_VSTATS) {
        prep_vstats(bid, smem, vc, vb, featpad);
    } else if (bid < NB_VSTATS + NB_HCONV) {
        prep_hconv(bid - NB_VSTATS, smem, h, featpad);
    } else {
        prep_w1t(bid - NB_VSTATS - NB_HCONV, smem, W1, w1t);
    }
}

// ---------------- Kernel 2: GEMM1 (+b1, ReLU) -> bf16 hidden --------------------------
// r13 structure + launch_bounds(256,4) (r14: dropped out of top-5, ~28-30 us).
__global__ __launch_bounds__(256, 4) void k_gemm(
        const unsigned short* __restrict__ A,   // featpad [16384][1088] (swizzled)
        const unsigned short* __restrict__ Bt,  // w1t [1152][1088] (swizzled)
        const float* __restrict__ b1,
        unsigned short* __restrict__ hidden) {  // [16384][1152] linear
    __shared__ unsigned short As[128 * 64];   // 16 KB, linear
    __shared__ unsigned short Bs[128 * 64];   // 16 KB, linear
    __shared__ float b1s[128];

    int tid = threadIdx.x;
    int lane = tid & 63;
    int wid = tid >> 6;

    int id = blockIdx.x;            // 0..1151
    int xcd = id & 7;
    int slot = id >> 3;             // 0..143
    int mt = xcd * 16 + slot / NT_N;
    int nt = slot % NT_N;

    if (tid < 128) {
        int ncol = nt * 128 + tid;
        b1s[tid] = (ncol < F_DIM) ? b1[ncol] : 0.f;
    }

    f32x4 acc[4][4] = {};
    int wm = wid >> 1, wn = wid & 1;

    const unsigned short* aSrc = A  + ((size_t)(mt * 128 + wid * 32 + (lane >> 3))) * KP + (lane & 7) * 8;
    const unsigned short* bSrc = Bt + ((size_t)(nt * 128 + wid * 32 + (lane >> 3))) * KP + (lane & 7) * 8;
    unsigned short* aDst = As + wid * 32 * 64;
    unsigned short* bDst = Bs + wid * 32 * 64;

    for (int kt = 0; kt < KP / 64; ++kt) {
        __syncthreads();
        #pragma unroll
        for (int i = 0; i < 4; ++i) {
            gload16(aSrc + kt * 64 + (size_t)i * 8 * KP, aDst + i * 8 * 64);
            gload16(bSrc + kt * 64 + (size_t)i * 8 * KP, bDst + i * 8 * 64);
        }
        __syncthreads();
        #pragma unroll
        for (int kk = 0; kk < 2; ++kk) {
            bf16x8 af[4], bfr[4];
            int klane = kk * 32 + ((lane >> 4) << 3);
            #pragma unroll
            for (int m = 0; m < 4; ++m) {
                int arow = wm * 64 + m * 16 + (lane & 15);
                int abyte = arow * 128 + ((klane * 2) ^ ((arow & 7) << 4));
                af[m] = *(const bf16x8*)((const char*)As + abyte);
            }
            #pragma unroll
            for (int n = 0; n < 4; ++n) {
                int brow = wn * 64 + n * 16 + (lane & 15);
                int bbyte = brow * 128 + ((klane * 2) ^ ((brow & 7) << 4));
                bfr[n] = *(const bf16x8*)((const char*)Bs + bbyte);
            }
            #pragma unroll
            for (int m = 0; m < 4; ++m)
                #pragma unroll
                for (int n = 0; n < 4; ++n)
                    acc[m][n] = __builtin_amdgcn_mfma_f32_16x16x32_bf16(af[m], bfr[n], acc[m][n], 0, 0, 0);
        }
    }

    #pragma unroll
    for (int m = 0; m < 4; ++m) {
        #pragma unroll
        for (int n = 0; n < 4; ++n) {
            int coll = wn * 64 + n * 16 + (lane & 15);
            int col = nt * 128 + coll;
            #pragma unroll
            for (int r = 0; r < 4; ++r) {
                int row = mt * 128 + wm * 64 + m * 16 + ((lane >> 4) << 2) + r;
                float v = acc[m][n][r] + b1s[coll];
                hidden[(size_t)row * NP + col] = f2bf(fmaxf(v, 0.f));
            }
        }
    }
}

// ---------------- Kernel 3: out = hidden @ W2 + b2 (memory-bound stream) -------------
__global__ __launch_bounds__(256) void k_head(const unsigned short* __restrict__ hidden,
                                              const float* __restrict__ W2,
                                              const float* __restrict__ b2,
                                              float* __restrict__ out) {
    __shared__ float W2s[NP * 5];   // 23,040 B
    int tid = threadIdx.x;
    for (int idx = tid; idx < NP * 5; idx += 256) {
        int n = idx / 5, j = idx % 5;
        W2s[idx] = (n < F_DIM) ? W2[n * 5 + j] : 0.f;
    }
    __syncthreads();

    int wid = tid >> 6, lane = tid & 63;
    int row = blockIdx.x * 16 + wid * 4 + (lane >> 4);   // 16 rows/block
    int seg = lane & 15;                                  // 16 lanes per row, 72 cols each
    const unsigned short* hr = hidden + (size_t)row * NP + seg * 72;

    float s[5] = {0.f, 0.f, 0.f, 0.f, 0.f};
    #pragma unroll
    for (int c = 0; c < 9; ++c) {
        union { uint4 v; unsigned short us[8]; } pk;
        pk.v = *(const uint4*)(hr + c * 8);
        #pragma unroll
        for (int e = 0; e < 8; ++e) {
            float hv = bf2f(pk.us[e]);
            int col = seg * 72 + c * 8 + e;
            #pragma unroll
            for (int j = 0; j < 5; ++j) s[j] += hv * W2s[col * 5 + j];
        }
    }
    #pragma unroll
    for (int o = 1; o < 16; o <<= 1) {
        #pragma unroll
        for (int j = 0; j < 5; ++j) s[j] += __shfl_xor(s[j], o);
    }
    if (seg == 0) {
        #pragma unroll
        for (int j = 0; j < 5; ++j) out[(size_t)row * 5 + j] = s[j] + b2[j];
    }
}

extern "C" void kernel_launch(void* const* d_in, const int* in_sizes, int n_in,
                              void* d_out, int out_size, void* d_ws, size_t ws_size,
                              hipStream_t stream) {
    const float* h_final   = (const float*)d_in[0];
    const float* v_current = (const float*)d_in[1];
    const float* v_basin   = (const float*)d_in[2];
    const float* W1        = (const float*)d_in[3];
    const float* b1        = (const float*)d_in[4];
    const float* W2        = (const float*)d_in[5];
    const float* b2        = (const float*)d_in[6];
    float* out = (float*)d_out;

    char* ws = (char*)d_ws;
    unsigned short* featpad = (unsigned short*)ws;                       // 16384*1088*2 = 35,651,584 B
    unsigned short* w1t     = (unsigned short*)(ws + 35651584);          // 1152*1088*2  =  2,506,752 B
    unsigned short* hidden  = (unsigned short*)(ws + 35651584 + 2506752);// 16384*1152*2 = 37,748,736 B

    k_prep<<<dim3(NB_VSTATS + NB_HCONV + NB_W1T), dim3(256), 0, stream>>>(
        h_final, v_current, v_basin, W1, featpad, w1t);
    k_gemm<<<dim3(NT_N * NT_M), dim3(256), 0, stream>>>(featpad, w1t, b1, hidden);
    k_head<<<dim3(B_ROWS / 16), dim3(256), 0, stream>>>(hidden, W2, b2, out);
}